// Round 6
// baseline (783.730 us; speedup 1.0000x reference)
//
#include <hip/hip_runtime.h>
#include <math.h>

#define IN_C 128
#define HID_C 64
#define OUT_C 40

__device__ __forceinline__ float readlane_f(float v, int l) {
  return __uint_as_float(__builtin_amdgcn_readlane(__float_as_uint(v), l));
}

// ---- grid-stride int4 zero ----
__global__ void zero4_kernel(int4* __restrict__ p, long long n4) {
  long long i = (long long)blockIdx.x * blockDim.x + threadIdx.x;
  long long stride = (long long)gridDim.x * blockDim.x;
  for (; i < n4; i += stride) p[i] = make_int4(0, 0, 0, 0);
}

// ---- degree: count incoming edges (dst side), int atomics ----
__global__ void deg_kernel(const int* __restrict__ dst, int E,
                           int* __restrict__ deg) {
  int i = blockIdx.x * blockDim.x + threadIdx.x;
  int stride = gridDim.x * blockDim.x;
  for (int e = i; e < E; e += stride) atomicAdd(&deg[dst[e]], 1);
}

// ---- dinv[i] = rsqrt(deg[i] + 1)  (self-loop) ----
__global__ void dinv_kernel(const int* __restrict__ deg,
                            float* __restrict__ dinv, int n) {
  int i = blockIdx.x * blockDim.x + threadIdx.x;
  if (i < n) dinv[i] = rsqrtf((float)deg[i] + 1.0f);
}

// ---- scan stage 1: per-1024-chunk inclusive scan + chunk totals ----
__global__ __launch_bounds__(256) void scan1_kernel(
    const int* __restrict__ deg, int* __restrict__ S, int* __restrict__ BS,
    int n) {
  __shared__ int sums[256];
  int t = threadIdx.x;
  int i0 = blockIdx.x * 1024 + t * 4;
  int v0 = (i0 + 0 < n) ? deg[i0 + 0] : 0;
  int v1 = (i0 + 1 < n) ? deg[i0 + 1] : 0;
  int v2 = (i0 + 2 < n) ? deg[i0 + 2] : 0;
  int v3 = (i0 + 3 < n) ? deg[i0 + 3] : 0;
  v1 += v0; v2 += v1; v3 += v2;
  sums[t] = v3;
  __syncthreads();
  for (int off = 1; off < 256; off <<= 1) {
    int x = (t >= off) ? sums[t - off] : 0;
    __syncthreads();
    sums[t] += x;
    __syncthreads();
  }
  int excl = t ? sums[t - 1] : 0;
  if (i0 + 0 < n) S[i0 + 0] = v0 + excl;
  if (i0 + 1 < n) S[i0 + 1] = v1 + excl;
  if (i0 + 2 < n) S[i0 + 2] = v2 + excl;
  if (i0 + 3 < n) S[i0 + 3] = v3 + excl;
  if (t == 255) BS[blockIdx.x] = sums[255];
}

// ---- scan stage 2: exclusive scan of chunk totals (nb <= 128) ----
__global__ __launch_bounds__(128) void scan2_kernel(int* __restrict__ BS,
                                                    int nb) {
  __shared__ int s[128];
  int t = threadIdx.x;
  s[t] = (t < nb) ? BS[t] : 0;
  __syncthreads();
  for (int off = 1; off < 128; off <<= 1) {
    int x = (t >= off) ? s[t - off] : 0;
    __syncthreads();
    s[t] += x;
    __syncthreads();
  }
  if (t < nb) BS[t] = t ? s[t - 1] : 0;
}

// ---- scan stage 3: rowptr + cursor ----
__global__ void scan3_kernel(const int* __restrict__ S,
                             const int* __restrict__ BS,
                             const int* __restrict__ deg,
                             int* __restrict__ rowptr,
                             int* __restrict__ cursor, int n) {
  int i = blockIdx.x * blockDim.x + threadIdx.x;
  if (i < n) {
    int r = S[i] + BS[i >> 10];      // inclusive prefix = rowptr[i+1]
    rowptr[i + 1] = r;
    cursor[i] = r - deg[i];          // = rowptr[i]
    if (i == 0) rowptr[0] = 0;
  }
}

// ---- CSR fill: bucket src indices by dst ----
__global__ void fill_kernel(const int* __restrict__ eidx, int E,
                            int* __restrict__ cursor, int* __restrict__ csr) {
  int i = blockIdx.x * blockDim.x + threadIdx.x;
  int stride = gridDim.x * blockDim.x;
  for (int e = i; e < E; e += stride) {
    int s = eidx[e];
    int d = eidx[E + e];
    int pos = atomicAdd(&cursor[d], 1);
    csr[pos] = s;
  }
}

// ---- y' = dinv * (x @ W1): register-tiled, 64 nodes x 64 cols per block,
//      each thread 4x4 outputs, float4 LDS reads on both operands ----
#define XS_LD 132  // 128 + 4 pad: rows land on different banks for ty=0..3
__global__ __launch_bounds__(256) void gemm1_kernel(
    const float* __restrict__ x, const float* __restrict__ W1,
    const float* __restrict__ dinv, float* __restrict__ y, int n) {
  __shared__ float xs[64 * XS_LD];   // 33.8 KiB
  __shared__ float wsh[IN_C * HID_C];  // 32 KiB, [c][j]
  int t = threadIdx.x;
  int rowBase = blockIdx.x * 64;
  const float4* xf4 = (const float4*)x;
  const float4* wf4 = (const float4*)W1;
  // stage x tile (clamped rows) and W1
#pragma unroll
  for (int k = 0; k < 8; ++k) {
    int t4 = t + k * 256;            // 0..2047
    int row = t4 >> 5, c4 = t4 & 31;
    int gr = rowBase + row;
    if (gr >= n) gr = n - 1;
    *(float4*)&xs[row * XS_LD + c4 * 4] = xf4[(size_t)gr * 32 + c4];
    *(float4*)&wsh[t4 * 4] = wf4[t4];
  }
  __syncthreads();
  int tx = t & 15, ty = t >> 4;
  int i0 = ty * 4, j0 = tx * 4;
  float acc[4][4];
#pragma unroll
  for (int r = 0; r < 4; ++r)
#pragma unroll
    for (int j = 0; j < 4; ++j) acc[r][j] = 0.f;
#pragma unroll
  for (int c4 = 0; c4 < IN_C; c4 += 4) {
    float4 xv[4], wv[4];
#pragma unroll
    for (int r = 0; r < 4; ++r)
      xv[r] = *(const float4*)&xs[(i0 + r) * XS_LD + c4];
#pragma unroll
    for (int cc = 0; cc < 4; ++cc)
      wv[cc] = *(const float4*)&wsh[(c4 + cc) * HID_C + j0];
#pragma unroll
    for (int r = 0; r < 4; ++r) {
#pragma unroll
      for (int cc = 0; cc < 4; ++cc) {
        float xr = (&xv[r].x)[cc];
        acc[r][0] = fmaf(xr, wv[cc].x, acc[r][0]);
        acc[r][1] = fmaf(xr, wv[cc].y, acc[r][1]);
        acc[r][2] = fmaf(xr, wv[cc].z, acc[r][2]);
        acc[r][3] = fmaf(xr, wv[cc].w, acc[r][3]);
      }
    }
  }
#pragma unroll
  for (int r = 0; r < 4; ++r) {
    int i = rowBase + i0 + r;
    if (i < n) {
      float di = dinv[i];
      float4 v = make_float4(di * acc[r][0], di * acc[r][1],
                             di * acc[r][2], di * acc[r][3]);
      *(float4*)&y[(size_t)i * HID_C + j0] = v;
    }
  }
}

// ---- gather(y') + bias/ReLU + fused z' = dinv * (h @ W2) ----
// wave = node; two 32-lane halves each take alternate edges, float2 channels
__global__ __launch_bounds__(256) void gather_gemm2_kernel(
    const float2* __restrict__ y2, const int* __restrict__ rowptr,
    const int* __restrict__ csr, const float* __restrict__ dinv,
    const float* __restrict__ b1, const float* __restrict__ W2,
    float* __restrict__ z, int n) {
  int lane = threadIdx.x & 63;
  int half = lane >> 5;            // 0 or 1: edge sub-group
  int cl = lane & 31;              // channel-pair index (2cl, 2cl+1)
  bool actj = lane < OUT_C;
  float w2[HID_C];
#pragma unroll
  for (int c = 0; c < HID_C; ++c) w2[c] = actj ? W2[c * OUT_C + lane] : 0.f;
  float2 b1v = ((const float2*)b1)[cl];
  int wid = (int)((blockIdx.x * blockDim.x + threadIdx.x) >> 6);
  int nw = (int)((gridDim.x * blockDim.x) >> 6);
  for (int ii = wid; ii < n; ii += nw) {
    int i = __builtin_amdgcn_readfirstlane(ii);
    float2 acc = make_float2(0.f, 0.f);
    if (half == 0) acc = y2[(size_t)i * 32 + cl];   // self term y'[i]
    int e = rowptr[i] + half, end = rowptr[i + 1];
    for (; e + 2 < end; e += 4) {
      int s0 = csr[e], s1 = csr[e + 2];
      float2 v0 = y2[(size_t)s0 * 32 + cl];
      float2 v1 = y2[(size_t)s1 * 32 + cl];
      acc.x += v0.x + v1.x;
      acc.y += v0.y + v1.y;
    }
    for (; e < end; e += 2) {
      int s = csr[e];
      float2 v = y2[(size_t)s * 32 + cl];
      acc.x += v.x;
      acc.y += v.y;
    }
    // combine halves (lane ^ 32)
    acc.x += __shfl_xor(acc.x, 32);
    acc.y += __shfl_xor(acc.y, 32);
    float di = dinv[i];
    float hx = fmaf(di, acc.x, b1v.x);
    float hy = fmaf(di, acc.y, b1v.y);
    hx = hx > 0.f ? hx : 0.f;
    hy = hy > 0.f ? hy : 0.f;
    // z = h @ W2 via readlane broadcast; channel 2p at lane p (.x), 2p+1 (.y)
    float z0 = 0.f, z1 = 0.f;
#pragma unroll
    for (int p = 0; p < 32; ++p) {
      z0 = fmaf(readlane_f(hx, p), w2[2 * p], z0);
      z1 = fmaf(readlane_f(hy, p), w2[2 * p + 1], z1);
    }
    if (actj) z[(size_t)i * OUT_C + lane] = di * (z0 + z1);  // z' = dinv*z
  }
}

// ---- gather(z') + bias + log-softmax: 3 groups of 20 lanes, float2 ----
__global__ __launch_bounds__(256) void gather40_kernel(
    const float2* __restrict__ z2, const int* __restrict__ rowptr,
    const int* __restrict__ csr, const float* __restrict__ dinv,
    const float* __restrict__ b2, float* __restrict__ out, int n) {
  int lane = threadIdx.x & 63;
  int g = lane / 20;               // 0,1,2 active; 3 idle
  int p = lane % 20;               // channel-pair index (2p, 2p+1)
  bool act = g < 3;
  float2 b2v = ((const float2*)b2)[p < 20 ? p : 0];
  int wid = (int)((blockIdx.x * blockDim.x + threadIdx.x) >> 6);
  int nw = (int)((gridDim.x * blockDim.x) >> 6);
  for (int ii = wid; ii < n; ii += nw) {
    int i = __builtin_amdgcn_readfirstlane(ii);
    float2 acc = make_float2(0.f, 0.f);
    if (g == 0) acc = z2[(size_t)i * 20 + p];       // self term z'[i]
    int e = rowptr[i] + g, end = rowptr[i + 1];
    if (act) {
      for (; e + 3 < end; e += 6) {
        int s0 = csr[e], s1 = csr[e + 3];
        float2 v0 = z2[(size_t)s0 * 20 + p];
        float2 v1 = z2[(size_t)s1 * 20 + p];
        acc.x += v0.x + v1.x;
        acc.y += v0.y + v1.y;
      }
      for (; e < end; e += 3) {
        int s = csr[e];
        float2 v = z2[(size_t)s * 20 + p];
        acc.x += v.x;
        acc.y += v.y;
      }
    }
    // combine three groups: totals for pair p = lanes p, p+20, p+40
    float ax1 = __shfl(acc.x, p + 20), ax2 = __shfl(acc.x, p + 40);
    float ay1 = __shfl(acc.y, p + 20), ay2 = __shfl(acc.y, p + 40);
    float tx = acc.x + ax1 + ax2;
    float ty = acc.y + ay1 + ay2;
    float di = dinv[i];
    bool own = lane < 20;
    float ox = own ? fmaf(di, tx, b2v.x) : -INFINITY;
    float oy = own ? fmaf(di, ty, b2v.y) : -INFINITY;
    // max over 40 channels: pairwise + butterfly within 32-lane half
    float m = fmaxf(ox, oy);
    for (int off = 16; off; off >>= 1) m = fmaxf(m, __shfl_xor(m, off));
    float ex = own ? expf(ox - m) + expf(oy - m) : 0.f;
    float s = ex;
    for (int off = 16; off; off >>= 1) s += __shfl_xor(s, off);
    if (own) {
      float l = m + logf(s);
      float2 o2 = make_float2(ox - l, oy - l);
      *(float2*)&out[(size_t)i * OUT_C + 2 * p] = o2;
    }
  }
}

extern "C" void kernel_launch(void* const* d_in, const int* in_sizes, int n_in,
                              void* d_out, int out_size, void* d_ws, size_t ws_size,
                              hipStream_t stream) {
  const float* x  = (const float*)d_in[0];
  const int* eidx = (const int*)d_in[1];   // harness delivers integers as int32
  const float* W1 = (const float*)d_in[2];
  const float* b1 = (const float*)d_in[3];
  const float* W2 = (const float*)d_in[4];
  const float* b2 = (const float*)d_in[5];
  float* out = (float*)d_out;

  int n = in_sizes[0] / IN_C;
  int E = in_sizes[1] / 2;

  size_t npad = ((size_t)n + 255) & ~(size_t)255;
  size_t Epad = ((size_t)E + 255) & ~(size_t)255;
  // layout (4-byte units)
  size_t o_dinv   = 0;
  size_t o_deg    = o_dinv + npad;
  size_t o_S      = o_deg + npad;
  size_t o_BS     = o_S + npad;
  size_t o_rowptr = o_BS + 256;
  size_t o_cursor = o_rowptr + npad + 256;
  size_t o_csr    = o_cursor + npad;
  size_t o_bufA   = o_csr + Epad;
  size_t o_bufB   = o_bufA + (size_t)n * HID_C;
  size_t needed   = (o_bufB + (size_t)n * HID_C) * 4;
  if (ws_size < needed) return;  // fail via absmax, not GPU fault

  float* ws  = (float*)d_ws;
  float* dinv = ws + o_dinv;
  int* deg    = (int*)(ws + o_deg);
  int* S      = (int*)(ws + o_S);
  int* BS     = (int*)(ws + o_BS);
  int* rowptr = (int*)(ws + o_rowptr);
  int* cursor = (int*)(ws + o_cursor);
  int* csr    = (int*)(ws + o_csr);
  float* bufA = ws + o_bufA;   // y' (n x 64)
  float* bufB = ws + o_bufB;   // z' (n x 40)

  int nb = (int)((n + 1023) / 1024);   // 98 for n=100k; scan2 supports <=128

  // ---- CSR build (shared by both layers) ----
  zero4_kernel<<<128, 256, 0, stream>>>((int4*)deg, (long long)(npad / 4));
  deg_kernel<<<1024, 256, 0, stream>>>(eidx + E, E, deg);
  dinv_kernel<<<(n + 255) / 256, 256, 0, stream>>>(deg, dinv, n);
  scan1_kernel<<<nb, 256, 0, stream>>>(deg, S, BS, n);
  scan2_kernel<<<1, 128, 0, stream>>>(BS, nb);
  scan3_kernel<<<(n + 255) / 256, 256, 0, stream>>>(S, BS, deg, rowptr, cursor, n);
  fill_kernel<<<1024, 256, 0, stream>>>(eidx, E, cursor, csr);

  // ---- layer 1 GEMM: y' = dinv * (x @ W1) ----
  gemm1_kernel<<<(n + 63) / 64, 256, 0, stream>>>(x, W1, dinv, bufA, n);
  // ---- gather(y') + bias/ReLU + z' = dinv * (h @ W2) (fused) ----
  gather_gemm2_kernel<<<1024, 256, 0, stream>>>((const float2*)bufA, rowptr,
                                                csr, dinv, b1, W2, bufB, n);
  // ---- gather(z') + bias + log-softmax ----
  gather40_kernel<<<1024, 256, 0, stream>>>((const float2*)bufB, rowptr, csr,
                                            dinv, b2, out, n);
}

// Round 7
// 258.350 us; speedup vs baseline: 3.0336x; 3.0336x over previous
//
#include <hip/hip_runtime.h>
#include <math.h>

#define IN_C 128
#define HID_C 64
#define OUT_C 40

__device__ __forceinline__ float readlane_f(float v, int l) {
  return __uint_as_float(__builtin_amdgcn_readlane(__float_as_uint(v), l));
}

// ---- grid-stride int4 zero ----
__global__ void zero4_kernel(int4* __restrict__ p, long long n4) {
  long long i = (long long)blockIdx.x * blockDim.x + threadIdx.x;
  long long stride = (long long)gridDim.x * blockDim.x;
  for (; i < n4; i += stride) p[i] = make_int4(0, 0, 0, 0);
}

// ---- degree: count incoming edges (dst side), int atomics ----
__global__ void deg_kernel(const int* __restrict__ dst, int E,
                           int* __restrict__ deg) {
  int i = blockIdx.x * blockDim.x + threadIdx.x;
  int stride = gridDim.x * blockDim.x;
  for (int e = i; e < E; e += stride) atomicAdd(&deg[dst[e]], 1);
}

// ---- dinv[i] = rsqrt(deg[i] + 1)  (self-loop) ----
__global__ void dinv_kernel(const int* __restrict__ deg,
                            float* __restrict__ dinv, int n) {
  int i = blockIdx.x * blockDim.x + threadIdx.x;
  if (i < n) dinv[i] = rsqrtf((float)deg[i] + 1.0f);
}

// ---- scan stage 1: per-1024-chunk inclusive scan + chunk totals ----
__global__ __launch_bounds__(256) void scan1_kernel(
    const int* __restrict__ deg, int* __restrict__ S, int* __restrict__ BS,
    int n) {
  __shared__ int sums[256];
  int t = threadIdx.x;
  int i0 = blockIdx.x * 1024 + t * 4;
  int v0 = (i0 + 0 < n) ? deg[i0 + 0] : 0;
  int v1 = (i0 + 1 < n) ? deg[i0 + 1] : 0;
  int v2 = (i0 + 2 < n) ? deg[i0 + 2] : 0;
  int v3 = (i0 + 3 < n) ? deg[i0 + 3] : 0;
  v1 += v0; v2 += v1; v3 += v2;
  sums[t] = v3;
  __syncthreads();
  for (int off = 1; off < 256; off <<= 1) {
    int x = (t >= off) ? sums[t - off] : 0;
    __syncthreads();
    sums[t] += x;
    __syncthreads();
  }
  int excl = t ? sums[t - 1] : 0;
  if (i0 + 0 < n) S[i0 + 0] = v0 + excl;
  if (i0 + 1 < n) S[i0 + 1] = v1 + excl;
  if (i0 + 2 < n) S[i0 + 2] = v2 + excl;
  if (i0 + 3 < n) S[i0 + 3] = v3 + excl;
  if (t == 255) BS[blockIdx.x] = sums[255];
}

// ---- scan stage 2: exclusive scan of chunk totals (nb <= 128) ----
__global__ __launch_bounds__(128) void scan2_kernel(int* __restrict__ BS,
                                                    int nb) {
  __shared__ int s[128];
  int t = threadIdx.x;
  s[t] = (t < nb) ? BS[t] : 0;
  __syncthreads();
  for (int off = 1; off < 128; off <<= 1) {
    int x = (t >= off) ? s[t - off] : 0;
    __syncthreads();
    s[t] += x;
    __syncthreads();
  }
  if (t < nb) BS[t] = t ? s[t - 1] : 0;
}

// ---- scan stage 3: rowptr + cursor ----
__global__ void scan3_kernel(const int* __restrict__ S,
                             const int* __restrict__ BS,
                             const int* __restrict__ deg,
                             int* __restrict__ rowptr,
                             int* __restrict__ cursor, int n) {
  int i = blockIdx.x * blockDim.x + threadIdx.x;
  if (i < n) {
    int r = S[i] + BS[i >> 10];      // inclusive prefix = rowptr[i+1]
    rowptr[i + 1] = r;
    cursor[i] = r - deg[i];          // = rowptr[i]
    if (i == 0) rowptr[0] = 0;
  }
}

// ---- CSR fill: bucket src indices by dst ----
__global__ void fill_kernel(const int* __restrict__ eidx, int E,
                            int* __restrict__ cursor, int* __restrict__ csr) {
  int i = blockIdx.x * blockDim.x + threadIdx.x;
  int stride = gridDim.x * blockDim.x;
  for (int e = i; e < E; e += stride) {
    int s = eidx[e];
    int d = eidx[E + e];
    int pos = atomicAdd(&cursor[d], 1);
    csr[pos] = s;
  }
}

// ---- y' = dinv * (x @ W1): 64x64 tile, K chunked by 64, 4x4 reg tile ----
#define XS_LD 68   // 64 + 4: float4-aligned, banks spread (68%32==4)
__global__ __launch_bounds__(256) void gemm1_kernel(
    const float* __restrict__ x, const float* __restrict__ W1,
    const float* __restrict__ dinv, float* __restrict__ y, int n) {
  __shared__ float xs[64 * XS_LD];    // 17.4 KiB
  __shared__ float wsh[64 * HID_C];   // 16 KiB, [k][j]
  int t = threadIdx.x;
  int rowBase = blockIdx.x * 64;
  const float4* xf4 = (const float4*)x;
  const float4* wf4 = (const float4*)W1;
  int tx = t & 15, ty = t >> 4;
  int i0 = ty * 4, j0 = tx * 4;
  float acc[4][4];
#pragma unroll
  for (int r = 0; r < 4; ++r)
#pragma unroll
    for (int j = 0; j < 4; ++j) acc[r][j] = 0.f;

  for (int kc = 0; kc < 2; ++kc) {           // K chunks of 64
    // stage x tile chunk: 64 rows x 64 cols = 1024 float4
#pragma unroll
    for (int k = 0; k < 4; ++k) {
      int t4 = t + k * 256;                  // 0..1023
      int row = t4 >> 4, c4 = t4 & 15;
      int gr = rowBase + row;
      if (gr >= n) gr = n - 1;
      *(float4*)&xs[row * XS_LD + c4 * 4] = xf4[(size_t)gr * 32 + kc * 16 + c4];
      // stage W chunk: k-row (kc*64+row), all 64 cols
      *(float4*)&wsh[row * HID_C + c4 * 4] = wf4[(size_t)(kc * 64 + row) * 16 + c4];
    }
    __syncthreads();
#pragma unroll 2
    for (int c4 = 0; c4 < 64; c4 += 4) {
      float4 xv[4], wv[4];
#pragma unroll
      for (int r = 0; r < 4; ++r)
        xv[r] = *(const float4*)&xs[(i0 + r) * XS_LD + c4];
#pragma unroll
      for (int cc = 0; cc < 4; ++cc)
        wv[cc] = *(const float4*)&wsh[(c4 + cc) * HID_C + j0];
#pragma unroll
      for (int r = 0; r < 4; ++r) {
#pragma unroll
        for (int cc = 0; cc < 4; ++cc) {
          float xr = (&xv[r].x)[cc];
          acc[r][0] = fmaf(xr, wv[cc].x, acc[r][0]);
          acc[r][1] = fmaf(xr, wv[cc].y, acc[r][1]);
          acc[r][2] = fmaf(xr, wv[cc].z, acc[r][2]);
          acc[r][3] = fmaf(xr, wv[cc].w, acc[r][3]);
        }
      }
    }
    __syncthreads();
  }
#pragma unroll
  for (int r = 0; r < 4; ++r) {
    int i = rowBase + i0 + r;
    if (i < n) {
      float di = dinv[i];
      float4 v = make_float4(di * acc[r][0], di * acc[r][1],
                             di * acc[r][2], di * acc[r][3]);
      *(float4*)&y[(size_t)i * HID_C + j0] = v;
    }
  }
}

// ---- gather(y') + bias/ReLU + fused z' = dinv * (h @ W2) ----
// wave = node; two 32-lane halves each take alternate edges, float2 channels
__global__ __launch_bounds__(256) void gather_gemm2_kernel(
    const float2* __restrict__ y2, const int* __restrict__ rowptr,
    const int* __restrict__ csr, const float* __restrict__ dinv,
    const float* __restrict__ b1, const float* __restrict__ W2,
    float* __restrict__ z, int n) {
  int lane = threadIdx.x & 63;
  int half = lane >> 5;            // 0 or 1: edge sub-group
  int cl = lane & 31;              // channel-pair index (2cl, 2cl+1)
  bool actj = lane < OUT_C;
  float w2[HID_C];
#pragma unroll
  for (int c = 0; c < HID_C; ++c) w2[c] = actj ? W2[c * OUT_C + lane] : 0.f;
  float2 b1v = ((const float2*)b1)[cl];
  int wid = (int)((blockIdx.x * blockDim.x + threadIdx.x) >> 6);
  int nw = (int)((gridDim.x * blockDim.x) >> 6);
  for (int ii = wid; ii < n; ii += nw) {
    int i = __builtin_amdgcn_readfirstlane(ii);
    float2 acc = make_float2(0.f, 0.f);
    if (half == 0) acc = y2[(size_t)i * 32 + cl];   // self term y'[i]
    int e = rowptr[i] + half, end = rowptr[i + 1];
    for (; e + 2 < end; e += 4) {
      int s0 = csr[e], s1 = csr[e + 2];
      float2 v0 = y2[(size_t)s0 * 32 + cl];
      float2 v1 = y2[(size_t)s1 * 32 + cl];
      acc.x += v0.x + v1.x;
      acc.y += v0.y + v1.y;
    }
    for (; e < end; e += 2) {
      int s = csr[e];
      float2 v = y2[(size_t)s * 32 + cl];
      acc.x += v.x;
      acc.y += v.y;
    }
    // combine halves (lane ^ 32)
    acc.x += __shfl_xor(acc.x, 32);
    acc.y += __shfl_xor(acc.y, 32);
    float di = dinv[i];
    float hx = fmaf(di, acc.x, b1v.x);
    float hy = fmaf(di, acc.y, b1v.y);
    hx = hx > 0.f ? hx : 0.f;
    hy = hy > 0.f ? hy : 0.f;
    // z = h @ W2 via readlane broadcast; channel 2p at lane p (.x), 2p+1 (.y)
    float z0 = 0.f, z1 = 0.f;
#pragma unroll
    for (int p = 0; p < 32; ++p) {
      z0 = fmaf(readlane_f(hx, p), w2[2 * p], z0);
      z1 = fmaf(readlane_f(hy, p), w2[2 * p + 1], z1);
    }
    if (actj) z[(size_t)i * OUT_C + lane] = di * (z0 + z1);  // z' = dinv*z
  }
}

// ---- gather(z') + bias + log-softmax: 3 groups of 20 lanes, float2 ----
__global__ __launch_bounds__(256) void gather40_kernel(
    const float2* __restrict__ z2, const int* __restrict__ rowptr,
    const int* __restrict__ csr, const float* __restrict__ dinv,
    const float* __restrict__ b2, float* __restrict__ out, int n) {
  int lane = threadIdx.x & 63;
  int g = lane / 20;               // 0,1,2 active; 3 idle
  int p = lane % 20;               // channel-pair index (2p, 2p+1)
  bool act = g < 3;
  float2 b2v = ((const float2*)b2)[p < 20 ? p : 0];
  int wid = (int)((blockIdx.x * blockDim.x + threadIdx.x) >> 6);
  int nw = (int)((gridDim.x * blockDim.x) >> 6);
  for (int ii = wid; ii < n; ii += nw) {
    int i = __builtin_amdgcn_readfirstlane(ii);
    float2 acc = make_float2(0.f, 0.f);
    if (g == 0) acc = z2[(size_t)i * 20 + p];       // self term z'[i]
    int e = rowptr[i] + g, end = rowptr[i + 1];
    if (act) {
      for (; e + 3 < end; e += 6) {
        int s0 = csr[e], s1 = csr[e + 3];
        float2 v0 = z2[(size_t)s0 * 20 + p];
        float2 v1 = z2[(size_t)s1 * 20 + p];
        acc.x += v0.x + v1.x;
        acc.y += v0.y + v1.y;
      }
      for (; e < end; e += 3) {
        int s = csr[e];
        float2 v = z2[(size_t)s * 20 + p];
        acc.x += v.x;
        acc.y += v.y;
      }
    }
    // combine three groups: totals for pair p = lanes p, p+20, p+40
    float ax1 = __shfl(acc.x, p + 20), ax2 = __shfl(acc.x, p + 40);
    float ay1 = __shfl(acc.y, p + 20), ay2 = __shfl(acc.y, p + 40);
    float tx = acc.x + ax1 + ax2;
    float ty = acc.y + ay1 + ay2;
    float di = dinv[i];
    bool own = lane < 20;
    float ox = own ? fmaf(di, tx, b2v.x) : -INFINITY;
    float oy = own ? fmaf(di, ty, b2v.y) : -INFINITY;
    // max over 40 channels: pairwise + butterfly within 32-lane half
    float m = fmaxf(ox, oy);
    for (int off = 16; off; off >>= 1) m = fmaxf(m, __shfl_xor(m, off));
    float ex = own ? expf(ox - m) + expf(oy - m) : 0.f;
    float s = ex;
    for (int off = 16; off; off >>= 1) s += __shfl_xor(s, off);
    if (own) {
      float l = m + logf(s);
      float2 o2 = make_float2(ox - l, oy - l);
      *(float2*)&out[(size_t)i * OUT_C + 2 * p] = o2;
    }
  }
}

extern "C" void kernel_launch(void* const* d_in, const int* in_sizes, int n_in,
                              void* d_out, int out_size, void* d_ws, size_t ws_size,
                              hipStream_t stream) {
  const float* x  = (const float*)d_in[0];
  const int* eidx = (const int*)d_in[1];   // harness delivers integers as int32
  const float* W1 = (const float*)d_in[2];
  const float* b1 = (const float*)d_in[3];
  const float* W2 = (const float*)d_in[4];
  const float* b2 = (const float*)d_in[5];
  float* out = (float*)d_out;

  int n = in_sizes[0] / IN_C;
  int E = in_sizes[1] / 2;

  size_t npad = ((size_t)n + 255) & ~(size_t)255;
  size_t Epad = ((size_t)E + 255) & ~(size_t)255;
  // layout (4-byte units)
  size_t o_dinv   = 0;
  size_t o_deg    = o_dinv + npad;
  size_t o_S      = o_deg + npad;
  size_t o_BS     = o_S + npad;
  size_t o_rowptr = o_BS + 256;
  size_t o_cursor = o_rowptr + npad + 256;
  size_t o_csr    = o_cursor + npad;
  size_t o_bufA   = o_csr + Epad;
  size_t o_bufB   = o_bufA + (size_t)n * HID_C;
  size_t needed   = (o_bufB + (size_t)n * HID_C) * 4;
  if (ws_size < needed) return;  // fail via absmax, not GPU fault

  float* ws  = (float*)d_ws;
  float* dinv = ws + o_dinv;
  int* deg    = (int*)(ws + o_deg);
  int* S      = (int*)(ws + o_S);
  int* BS     = (int*)(ws + o_BS);
  int* rowptr = (int*)(ws + o_rowptr);
  int* cursor = (int*)(ws + o_cursor);
  int* csr    = (int*)(ws + o_csr);
  float* bufA = ws + o_bufA;   // y' (n x 64)
  float* bufB = ws + o_bufB;   // z' (n x 40)

  int nb = (int)((n + 1023) / 1024);   // 98 for n=100k; scan2 supports <=128

  // ---- CSR build (shared by both layers) ----
  zero4_kernel<<<128, 256, 0, stream>>>((int4*)deg, (long long)(npad / 4));
  deg_kernel<<<1024, 256, 0, stream>>>(eidx + E, E, deg);
  dinv_kernel<<<(n + 255) / 256, 256, 0, stream>>>(deg, dinv, n);
  scan1_kernel<<<nb, 256, 0, stream>>>(deg, S, BS, n);
  scan2_kernel<<<1, 128, 0, stream>>>(BS, nb);
  scan3_kernel<<<(n + 255) / 256, 256, 0, stream>>>(S, BS, deg, rowptr, cursor, n);
  fill_kernel<<<1024, 256, 0, stream>>>(eidx, E, cursor, csr);

  // ---- layer 1 GEMM: y' = dinv * (x @ W1) ----
  gemm1_kernel<<<(n + 63) / 64, 256, 0, stream>>>(x, W1, dinv, bufA, n);
  // ---- gather(y') + bias/ReLU + z' = dinv * (h @ W2) (fused) ----
  gather_gemm2_kernel<<<1024, 256, 0, stream>>>((const float2*)bufA, rowptr,
                                                csr, dinv, b1, W2, bufB, n);
  // ---- gather(z') + bias + log-softmax ----
  gather40_kernel<<<1024, 256, 0, stream>>>((const float2*)bufB, rowptr, csr,
                                            dinv, b2, out, n);
}

// Round 8
// 229.353 us; speedup vs baseline: 3.4171x; 1.1264x over previous
//
#include <hip/hip_runtime.h>
#include <math.h>

#define IN_C 128
#define HID_C 64
#define OUT_C 40

__device__ __forceinline__ float readlane_f(float v, int l) {
  return __uint_as_float(__builtin_amdgcn_readlane(__float_as_uint(v), l));
}

// ---- grid-stride int4 zero ----
__global__ void zero4_kernel(int4* __restrict__ p, long long n4) {
  long long i = (long long)blockIdx.x * blockDim.x + threadIdx.x;
  long long stride = (long long)gridDim.x * blockDim.x;
  for (; i < n4; i += stride) p[i] = make_int4(0, 0, 0, 0);
}

// ---- degree: count incoming edges (dst side), int atomics ----
__global__ void deg_kernel(const int* __restrict__ dst, int E,
                           int* __restrict__ deg) {
  int i = blockIdx.x * blockDim.x + threadIdx.x;
  int stride = gridDim.x * blockDim.x;
  for (int e = i; e < E; e += stride) atomicAdd(&deg[dst[e]], 1);
}

// ---- dinv[i] = rsqrt(deg[i] + 1)  (self-loop) ----
__global__ void dinv_kernel(const int* __restrict__ deg,
                            float* __restrict__ dinv, int n) {
  int i = blockIdx.x * blockDim.x + threadIdx.x;
  if (i < n) dinv[i] = rsqrtf((float)deg[i] + 1.0f);
}

// ---- scan stage 1: per-1024-chunk inclusive scan + chunk totals ----
__global__ __launch_bounds__(256) void scan1_kernel(
    const int* __restrict__ deg, int* __restrict__ S, int* __restrict__ BS,
    int n) {
  __shared__ int sums[256];
  int t = threadIdx.x;
  int i0 = blockIdx.x * 1024 + t * 4;
  int v0 = (i0 + 0 < n) ? deg[i0 + 0] : 0;
  int v1 = (i0 + 1 < n) ? deg[i0 + 1] : 0;
  int v2 = (i0 + 2 < n) ? deg[i0 + 2] : 0;
  int v3 = (i0 + 3 < n) ? deg[i0 + 3] : 0;
  v1 += v0; v2 += v1; v3 += v2;
  sums[t] = v3;
  __syncthreads();
  for (int off = 1; off < 256; off <<= 1) {
    int x = (t >= off) ? sums[t - off] : 0;
    __syncthreads();
    sums[t] += x;
    __syncthreads();
  }
  int excl = t ? sums[t - 1] : 0;
  if (i0 + 0 < n) S[i0 + 0] = v0 + excl;
  if (i0 + 1 < n) S[i0 + 1] = v1 + excl;
  if (i0 + 2 < n) S[i0 + 2] = v2 + excl;
  if (i0 + 3 < n) S[i0 + 3] = v3 + excl;
  if (t == 255) BS[blockIdx.x] = sums[255];
}

// ---- scan stage 2: exclusive scan of chunk totals (nb <= 128) ----
__global__ __launch_bounds__(128) void scan2_kernel(int* __restrict__ BS,
                                                    int nb) {
  __shared__ int s[128];
  int t = threadIdx.x;
  s[t] = (t < nb) ? BS[t] : 0;
  __syncthreads();
  for (int off = 1; off < 128; off <<= 1) {
    int x = (t >= off) ? s[t - off] : 0;
    __syncthreads();
    s[t] += x;
    __syncthreads();
  }
  if (t < nb) BS[t] = t ? s[t - 1] : 0;
}

// ---- scan stage 3: rowptr + cursor ----
__global__ void scan3_kernel(const int* __restrict__ S,
                             const int* __restrict__ BS,
                             const int* __restrict__ deg,
                             int* __restrict__ rowptr,
                             int* __restrict__ cursor, int n) {
  int i = blockIdx.x * blockDim.x + threadIdx.x;
  if (i < n) {
    int r = S[i] + BS[i >> 10];      // inclusive prefix = rowptr[i+1]
    rowptr[i + 1] = r;
    cursor[i] = r - deg[i];          // = rowptr[i]
    if (i == 0) rowptr[0] = 0;
  }
}

// ---- CSR fill: bucket src indices by dst ----
__global__ void fill_kernel(const int* __restrict__ eidx, int E,
                            int* __restrict__ cursor, int* __restrict__ csr) {
  int i = blockIdx.x * blockDim.x + threadIdx.x;
  int stride = gridDim.x * blockDim.x;
  for (int e = i; e < E; e += stride) {
    int s = eidx[e];
    int d = eidx[E + e];
    int pos = atomicAdd(&cursor[d], 1);
    csr[pos] = s;
  }
}

// ---- y' = dinv * (x @ W1): 64x64 tile, K chunked by 64, 4x4 reg tile ----
#define XS_LD 68   // 64 + 4: float4-aligned, banks spread (68%32==4)
__global__ __launch_bounds__(256) void gemm1_kernel(
    const float* __restrict__ x, const float* __restrict__ W1,
    const float* __restrict__ dinv, float* __restrict__ y, int n) {
  __shared__ float xs[64 * XS_LD];    // 17.4 KiB
  __shared__ float wsh[64 * HID_C];   // 16 KiB, [k][j]
  int t = threadIdx.x;
  int rowBase = blockIdx.x * 64;
  const float4* xf4 = (const float4*)x;
  const float4* wf4 = (const float4*)W1;
  int tx = t & 15, ty = t >> 4;
  int i0 = ty * 4, j0 = tx * 4;
  float acc[4][4];
#pragma unroll
  for (int r = 0; r < 4; ++r)
#pragma unroll
    for (int j = 0; j < 4; ++j) acc[r][j] = 0.f;

  for (int kc = 0; kc < 2; ++kc) {           // K chunks of 64
#pragma unroll
    for (int k = 0; k < 4; ++k) {
      int t4 = t + k * 256;                  // 0..1023
      int row = t4 >> 4, c4 = t4 & 15;
      int gr = rowBase + row;
      if (gr >= n) gr = n - 1;
      *(float4*)&xs[row * XS_LD + c4 * 4] = xf4[(size_t)gr * 32 + kc * 16 + c4];
      *(float4*)&wsh[row * HID_C + c4 * 4] = wf4[(size_t)(kc * 64 + row) * 16 + c4];
    }
    __syncthreads();
#pragma unroll 2
    for (int c4 = 0; c4 < 64; c4 += 4) {
      float4 xv[4], wv[4];
#pragma unroll
      for (int r = 0; r < 4; ++r)
        xv[r] = *(const float4*)&xs[(i0 + r) * XS_LD + c4];
#pragma unroll
      for (int cc = 0; cc < 4; ++cc)
        wv[cc] = *(const float4*)&wsh[(c4 + cc) * HID_C + j0];
#pragma unroll
      for (int r = 0; r < 4; ++r) {
#pragma unroll
        for (int cc = 0; cc < 4; ++cc) {
          float xr = (&xv[r].x)[cc];
          acc[r][0] = fmaf(xr, wv[cc].x, acc[r][0]);
          acc[r][1] = fmaf(xr, wv[cc].y, acc[r][1]);
          acc[r][2] = fmaf(xr, wv[cc].z, acc[r][2]);
          acc[r][3] = fmaf(xr, wv[cc].w, acc[r][3]);
        }
      }
    }
    __syncthreads();
  }
#pragma unroll
  for (int r = 0; r < 4; ++r) {
    int i = rowBase + i0 + r;
    if (i < n) {
      float di = dinv[i];
      float4 v = make_float4(di * acc[r][0], di * acc[r][1],
                             di * acc[r][2], di * acc[r][3]);
      *(float4*)&y[(size_t)i * HID_C + j0] = v;
    }
  }
}

// ---- gather(y') + bias/ReLU + fused z' = dinv * (h @ W2) ----
// wave = node; 4 quarters of 16 lanes, each takes every 4th edge, float4 ch
__global__ __launch_bounds__(256) void gather_gemm2_kernel(
    const float4* __restrict__ y4, const int* __restrict__ rowptr,
    const int* __restrict__ csr, const float* __restrict__ dinv,
    const float* __restrict__ b1, const float* __restrict__ W2,
    float* __restrict__ z, int n) {
  int lane = threadIdx.x & 63;
  int grp = lane >> 4;             // 0..3: edge sub-group
  int q = lane & 15;               // float4 index (channels 4q..4q+3)
  bool actj = lane < OUT_C;
  float w2[HID_C];
#pragma unroll
  for (int c = 0; c < HID_C; ++c) w2[c] = actj ? W2[c * OUT_C + lane] : 0.f;
  float4 b1v = ((const float4*)b1)[q];
  int wid = (int)((blockIdx.x * blockDim.x + threadIdx.x) >> 6);
  int nw = (int)((gridDim.x * blockDim.x) >> 6);
  for (int ii = wid; ii < n; ii += nw) {
    int i = __builtin_amdgcn_readfirstlane(ii);
    float4 acc = make_float4(0.f, 0.f, 0.f, 0.f);
    if (grp == 0) acc = y4[(size_t)i * 16 + q];       // self term y'[i]
    int e = rowptr[i] + grp, end = rowptr[i + 1];
    for (; e + 4 < end; e += 8) {
      int s0 = csr[e], s1 = csr[e + 4];
      float4 v0 = y4[(size_t)s0 * 16 + q];
      float4 v1 = y4[(size_t)s1 * 16 + q];
      acc.x += v0.x + v1.x;
      acc.y += v0.y + v1.y;
      acc.z += v0.z + v1.z;
      acc.w += v0.w + v1.w;
    }
    for (; e < end; e += 4) {
      int s = csr[e];
      float4 v = y4[(size_t)s * 16 + q];
      acc.x += v.x; acc.y += v.y; acc.z += v.z; acc.w += v.w;
    }
    // combine quarters (xor 16, xor 32)
    acc.x += __shfl_xor(acc.x, 16); acc.y += __shfl_xor(acc.y, 16);
    acc.z += __shfl_xor(acc.z, 16); acc.w += __shfl_xor(acc.w, 16);
    acc.x += __shfl_xor(acc.x, 32); acc.y += __shfl_xor(acc.y, 32);
    acc.z += __shfl_xor(acc.z, 32); acc.w += __shfl_xor(acc.w, 32);
    float di = dinv[i];
    float4 hv;
    hv.x = fmaf(di, acc.x, b1v.x); hv.x = hv.x > 0.f ? hv.x : 0.f;
    hv.y = fmaf(di, acc.y, b1v.y); hv.y = hv.y > 0.f ? hv.y : 0.f;
    hv.z = fmaf(di, acc.z, b1v.z); hv.z = hv.z > 0.f ? hv.z : 0.f;
    hv.w = fmaf(di, acc.w, b1v.w); hv.w = hv.w > 0.f ? hv.w : 0.f;
    // z = h @ W2 via readlane broadcast (all lanes hold identical hv per q)
    float z0 = 0.f, z1 = 0.f;
#pragma unroll
    for (int p = 0; p < 16; ++p) {
      z0 = fmaf(readlane_f(hv.x, p), w2[4 * p + 0], z0);
      z1 = fmaf(readlane_f(hv.y, p), w2[4 * p + 1], z1);
      z0 = fmaf(readlane_f(hv.z, p), w2[4 * p + 2], z0);
      z1 = fmaf(readlane_f(hv.w, p), w2[4 * p + 3], z1);
    }
    if (actj) z[(size_t)i * OUT_C + lane] = di * (z0 + z1);  // z' = dinv*z
  }
}

// ---- gather(z') + bias + log-softmax: 4 quarters, q<10 active, float4 ----
__global__ __launch_bounds__(256) void gather40_kernel(
    const float4* __restrict__ z4, const int* __restrict__ rowptr,
    const int* __restrict__ csr, const float* __restrict__ dinv,
    const float* __restrict__ b2, float* __restrict__ out, int n) {
  int lane = threadIdx.x & 63;
  int grp = lane >> 4;             // quarter 0..3: edge sub-group
  int q = lane & 15;               // float4 index; active q<10 (40 ch)
  bool act = q < 10;
  float4 b2v = ((const float4*)b2)[act ? q : 0];
  int wid = (int)((blockIdx.x * blockDim.x + threadIdx.x) >> 6);
  int nw = (int)((gridDim.x * blockDim.x) >> 6);
  for (int ii = wid; ii < n; ii += nw) {
    int i = __builtin_amdgcn_readfirstlane(ii);
    float4 acc = make_float4(0.f, 0.f, 0.f, 0.f);
    if (grp == 0 && act) acc = z4[(size_t)i * 10 + q];    // self term z'[i]
    int e = rowptr[i] + grp, end = rowptr[i + 1];
    if (act) {
      for (; e + 4 < end; e += 8) {
        int s0 = csr[e], s1 = csr[e + 4];
        float4 v0 = z4[(size_t)s0 * 10 + q];
        float4 v1 = z4[(size_t)s1 * 10 + q];
        acc.x += v0.x + v1.x;
        acc.y += v0.y + v1.y;
        acc.z += v0.z + v1.z;
        acc.w += v0.w + v1.w;
      }
      for (; e < end; e += 4) {
        int s = csr[e];
        float4 v = z4[(size_t)s * 10 + q];
        acc.x += v.x; acc.y += v.y; acc.z += v.z; acc.w += v.w;
      }
    }
    // combine quarters (inactive lanes hold zeros everywhere)
    acc.x += __shfl_xor(acc.x, 16); acc.y += __shfl_xor(acc.y, 16);
    acc.z += __shfl_xor(acc.z, 16); acc.w += __shfl_xor(acc.w, 16);
    acc.x += __shfl_xor(acc.x, 32); acc.y += __shfl_xor(acc.y, 32);
    acc.z += __shfl_xor(acc.z, 32); acc.w += __shfl_xor(acc.w, 32);
    float di = dinv[i];
    float4 o;
    o.x = fmaf(di, acc.x, b2v.x);
    o.y = fmaf(di, acc.y, b2v.y);
    o.z = fmaf(di, acc.z, b2v.z);
    o.w = fmaf(di, acc.w, b2v.w);
    // max over 40 ch: per-lane max4, butterfly within 16-lane quarter
    float m = act ? fmaxf(fmaxf(o.x, o.y), fmaxf(o.z, o.w)) : -INFINITY;
    for (int off = 8; off; off >>= 1) m = fmaxf(m, __shfl_xor(m, off));
    float ex = act ? (expf(o.x - m) + expf(o.y - m) +
                      expf(o.z - m) + expf(o.w - m)) : 0.f;
    float s = ex;
    for (int off = 8; off; off >>= 1) s += __shfl_xor(s, off);
    if (lane < 16 && act) {       // quarter 0 stores, float4 per lane
      float l = m + logf(s);
      float4 o2 = make_float4(o.x - l, o.y - l, o.z - l, o.w - l);
      *(float4*)&out[(size_t)i * OUT_C + 4 * q] = o2;
    }
  }
}

extern "C" void kernel_launch(void* const* d_in, const int* in_sizes, int n_in,
                              void* d_out, int out_size, void* d_ws, size_t ws_size,
                              hipStream_t stream) {
  const float* x  = (const float*)d_in[0];
  const int* eidx = (const int*)d_in[1];   // harness delivers integers as int32
  const float* W1 = (const float*)d_in[2];
  const float* b1 = (const float*)d_in[3];
  const float* W2 = (const float*)d_in[4];
  const float* b2 = (const float*)d_in[5];
  float* out = (float*)d_out;

  int n = in_sizes[0] / IN_C;
  int E = in_sizes[1] / 2;

  size_t npad = ((size_t)n + 255) & ~(size_t)255;
  size_t Epad = ((size_t)E + 255) & ~(size_t)255;
  // layout (4-byte units)
  size_t o_dinv   = 0;
  size_t o_deg    = o_dinv + npad;
  size_t o_S      = o_deg + npad;
  size_t o_BS     = o_S + npad;
  size_t o_rowptr = o_BS + 256;
  size_t o_cursor = o_rowptr + npad + 256;
  size_t o_csr    = o_cursor + npad;
  size_t o_bufA   = o_csr + Epad;
  size_t o_bufB   = o_bufA + (size_t)n * HID_C;
  size_t needed   = (o_bufB + (size_t)n * HID_C) * 4;
  if (ws_size < needed) return;  // fail via absmax, not GPU fault

  float* ws  = (float*)d_ws;
  float* dinv = ws + o_dinv;
  int* deg    = (int*)(ws + o_deg);
  int* S      = (int*)(ws + o_S);
  int* BS     = (int*)(ws + o_BS);
  int* rowptr = (int*)(ws + o_rowptr);
  int* cursor = (int*)(ws + o_cursor);
  int* csr    = (int*)(ws + o_csr);
  float* bufA = ws + o_bufA;   // y' (n x 64)
  float* bufB = ws + o_bufB;   // z' (n x 40)

  int nb = (int)((n + 1023) / 1024);   // 98 for n=100k; scan2 supports <=128

  // ---- CSR build (shared by both layers) ----
  zero4_kernel<<<128, 256, 0, stream>>>((int4*)deg, (long long)(npad / 4));
  deg_kernel<<<1024, 256, 0, stream>>>(eidx + E, E, deg);
  dinv_kernel<<<(n + 255) / 256, 256, 0, stream>>>(deg, dinv, n);
  scan1_kernel<<<nb, 256, 0, stream>>>(deg, S, BS, n);
  scan2_kernel<<<1, 128, 0, stream>>>(BS, nb);
  scan3_kernel<<<(n + 255) / 256, 256, 0, stream>>>(S, BS, deg, rowptr, cursor, n);
  fill_kernel<<<1024, 256, 0, stream>>>(eidx, E, cursor, csr);

  // ---- layer 1 GEMM: y' = dinv * (x @ W1) ----
  gemm1_kernel<<<(n + 63) / 64, 256, 0, stream>>>(x, W1, dinv, bufA, n);
  // ---- gather(y') + bias/ReLU + z' = dinv * (h @ W2) (fused) ----
  gather_gemm2_kernel<<<2048, 256, 0, stream>>>((const float4*)bufA, rowptr,
                                                csr, dinv, b1, W2, bufB, n);
  // ---- gather(z') + bias + log-softmax ----
  gather40_kernel<<<2048, 256, 0, stream>>>((const float4*)bufB, rowptr, csr,
                                            dinv, b2, out, n);
}